// Round 16
// baseline (183.307 us; speedup 1.0000x reference)
//
#include <hip/hip_runtime.h>
#include <hip/hip_fp16.h>
#include <hip/hip_bf16.h>
#include <stdint.h>
#include <stddef.h>

#define C_INC 320
#define KREAL 2880
#define KPAD  2944
#define OUT_F 384
#define RANK  32
#define HH    64
#define WW    64
#define NTOK  16384
#define NCH   16         // channel chunks for im2q kernel
#define CCH   20         // channels per chunk (16*20=320)
#define QSTR  76         // qbuf row stride bytes (max 8ch*9=72 +4 pad)
#define BK    128        // k_gemm K-tile

typedef int   vi4 __attribute__((ext_vector_type(4)));
typedef float v4f __attribute__((ext_vector_type(4)));
typedef short s8v __attribute__((ext_vector_type(8)));

// async global->LDS, 16B per lane; LDS dest is wave-uniform base + lane*16
static __device__ __forceinline__ void async16(const void* g, void* l) {
    __builtin_amdgcn_global_load_lds(
        (const __attribute__((address_space(1))) unsigned int*)g,
        (__attribute__((address_space(3))) unsigned int*)l, 16, 0, 0);
}

static __device__ __forceinline__ unsigned short f2bf(float f) {
    __hip_bfloat16 h = __float2bfloat16(f);   // RNE
    union { __hip_bfloat16 h; unsigned short u; } c; c.h = h; return c.u;
}

// ---------------- quantize weights per output row (exact IEEE div) ----------------
__global__ __launch_bounds__(256) void kq_w(const float* __restrict__ w,
                                            int8_t* __restrict__ qw,
                                            float* __restrict__ sw) {
    int o = blockIdx.x;
    const float* row = w + (size_t)o * KPAD;
    float m = 0.f;
    for (int k = threadIdx.x; k < KPAD; k += 256) m = fmaxf(m, fabsf(row[k]));
    #pragma unroll
    for (int off = 32; off > 0; off >>= 1) m = fmaxf(m, __shfl_down(m, off, 64));
    __shared__ float red[4];
    __shared__ float sval;
    if ((threadIdx.x & 63) == 0) red[threadIdx.x >> 6] = m;
    __syncthreads();
    if (threadIdx.x == 0) {
        float mm = fmaxf(fmaxf(red[0], red[1]), fmaxf(red[2], red[3]));
        sval = fmaxf(mm / 7.0f, 1e-8f);
        sw[o] = sval;
    }
    __syncthreads();
    float s = sval;
    for (int k = threadIdx.x; k < KPAD; k += 256) {
        float q = rintf(row[k] / s);          // IEEE div + RNE, matches np
        q = fminf(fmaxf(q, -8.f), 7.f);
        qw[(size_t)o * KPAD + k] = (int8_t)q;
    }
}

// ---------------- sx = max over 3x3 neighborhood of per-pixel channel max / 7 ----------------
__global__ __launch_bounds__(256) void k_sx(const float* __restrict__ mb,
                                            float* __restrict__ sx) {
    int p = blockIdx.x * 256 + threadIdx.x;
    int n = p >> 12, hw = p & 4095;
    int h = hw >> 6, w = hw & 63;
    const float* pl = mb + (n << 12);
    float m = 0.f;
    #pragma unroll
    for (int di = -1; di <= 1; ++di)
        #pragma unroll
        for (int dj = -1; dj <= 1; ++dj) {
            int hh = h + di, ww = w + dj;
            if ((unsigned)hh < (unsigned)HH && (unsigned)ww < (unsigned)WW)
                m = fmaxf(m, pl[(hh << 6) + ww]);
        }
    sx[p] = fmaxf(m / 7.0f, 1e-8f);
}

// ---------------- im2col quantize only ----------------
__global__ __launch_bounds__(256) void k_im2q(const float* __restrict__ x,
                                              const float* __restrict__ sx,
                                              int8_t* __restrict__ qx) {
    __shared__ int8_t qbuf[256 * QSTR];    // 19456 B (256 token rows)
    const int pstart[4] = {0, 8, 16, 20};  // phase channel starts (sizes 8,8,4)
    const int phoff[3]  = {0, 72, 144};    // byte offset within this chunk's k-range

    int tid = threadIdx.x;                 // 0..255
    int rg = blockIdx.x;                   // 0..63
    int cc = blockIdx.y;                   // 0..15
    int n = rg >> 4, h4 = rg & 15;
    int wid = tid >> 6, lane = tid & 63;
    int ha = h4 * 4 + wid;                 // this thread's image row
    int c0 = cc * CCH;

    int ta = (n << 12) + (ha << 6) + lane; // this thread's token
    float inva = 1.0f / sx[ta];
    const float* xrowa = x + ((size_t)(n * C_INC) + c0) * 4096 + (ha << 6) + lane;
    bool hok0a = (ha > 0), hok2a = (ha < 63);
    bool wok0 = (lane > 0), wok2 = (lane < 63);
    int bt = (n << 12) + (h4 << 8);        // block's first token (4 rows * 64)
    int qra = tid;                          // qbuf row for this token

    for (int ph = 0; ph < 3; ++ph) {
        int ps = pstart[ph], pch = pstart[ph + 1] - ps;
        __syncthreads();   // prior phase's qbuf writes complete
        if (ph > 0) {      // flush previous phase (8 ch = 18 dwords/row, 256 rows)
            for (int i = tid; i < 256 * 18; i += 256) {
                int row = i / 18, col = i - row * 18;
                *(unsigned int*)&qx[(size_t)(bt + row) * KPAD + cc * 180 + phoff[ph - 1] + col * 4] =
                    *(unsigned int*)&qbuf[row * QSTR + col * 4];
            }
        }
        __syncthreads();   // flush reads done before qbuf overwrite

        // initial row loads for this phase
        const float* xca = xrowa + (size_t)ps * 4096;
        float r0a = hok0a ? xca[-64] : 0.f, r1a = xca[0], r2a = hok2a ? xca[64] : 0.f;

        for (int cl = 0; cl < pch; ++cl) {
            // prefetch next channel's rows
            float p0a = 0.f, p1a = 0.f, p2a = 0.f;
            if (cl + 1 < pch) {
                const float* xna = xrowa + (size_t)(ps + cl + 1) * 4096;
                p0a = hok0a ? xna[-64] : 0.f; p1a = xna[0]; p2a = hok2a ? xna[64] : 0.f;
            }
            // horizontal neighbors: shfl executed by ALL lanes, then select
            float va[9];
            {
                float u0 = __shfl_up(r0a, 1, 64), d0 = __shfl_down(r0a, 1, 64);
                float u1 = __shfl_up(r1a, 1, 64), d1 = __shfl_down(r1a, 1, 64);
                float u2 = __shfl_up(r2a, 1, 64), d2 = __shfl_down(r2a, 1, 64);
                va[0] = wok0 ? u0 : 0.f; va[1] = r0a; va[2] = wok2 ? d0 : 0.f;
                va[3] = wok0 ? u1 : 0.f; va[4] = r1a; va[5] = wok2 ? d1 : 0.f;
                va[6] = wok0 ? u2 : 0.f; va[7] = r2a; va[8] = wok2 ? d2 : 0.f;
            }
            #pragma unroll
            for (int u = 0; u < 9; ++u) {
                float qa = rintf(va[u] * inva);
                qa = fminf(fmaxf(qa, -8.f), 7.f);
                qbuf[qra * QSTR + cl * 9 + u] = (int8_t)qa;
            }
            r0a = p0a; r1a = p1a; r2a = p2a;
        }
    }

    // flush phase 2 (4 ch = 9 dwords; cc==15 adds 16 zero dwords for k-pad)
    __syncthreads();
    if (cc == NCH - 1) {
        for (int i = tid; i < 256 * 25; i += 256) {
            int row = i / 25, col = i - row * 25;
            unsigned int vdw = (col < 9) ? *(unsigned int*)&qbuf[row * QSTR + col * 4] : 0u;
            *(unsigned int*)&qx[(size_t)(bt + row) * KPAD + cc * 180 + 144 + col * 4] = vdw;
        }
    } else {
        for (int i = tid; i < 256 * 9; i += 256) {
            int row = i / 9, col = i - row * 9;
            *(unsigned int*)&qx[(size_t)(bt + row) * KPAD + cc * 180 + 144 + col * 4] =
                *(unsigned int*)&qbuf[row * QSTR + col * 4];
        }
    }
}

// ---------------- k_down v12: S = pd^T @ x + fused channel absmax, 3x96 m-split ----------------
__global__ __launch_bounds__(256) void k_down(const float* __restrict__ x,
                                              const float* __restrict__ pd,
                                              __half* __restrict__ Sh,
                                              float* __restrict__ mb) {
    __shared__ unsigned short Abuf[96 * 168];    // 32256 B, row=ml, col=phase-local c (pad 160->168)
    int tid = threadIdx.x;
    int lid = blockIdx.x + 3 * blockIdx.y;  // 0..767
    int xcd = lid & 7, pos = lid >> 3;      // pos 0..95
    int mthird = pos % 3;                   // fastest: siblings adjacent on same XCD
    int nb = xcd * 32 + pos / 3;            // 0..255 (64-token chunk id)
    int w = tid >> 6, lane = tid & 63;
    int lg = lane >> 4, lr = lane & 15;
    int n = nb >> 6;                        // image index (64 chunks per image)
    int hw0 = (nb & 63) * 64 + w * 16;      // wave's 16-token span
    const float* xn = x + (size_t)n * (C_INC * 4096);

    v4f acc[6];
    #pragma unroll
    for (int mt = 0; mt < 6; ++mt) acc[mt] = (v4f)0.f;
    float m0v = 0.f;                        // channel absmax for this wave's 16 tokens

    for (int p = 0; p < 2; ++p) {
        __syncthreads();   // prior phase's a-frag reads complete
        // stage A: src pd slice is contiguous per channel: pd[c*288 + m_global]
        for (int i = tid; i < 160 * 96; i += 256) {
            int cl = i / 96, ml = i - cl * 96;
            int c = p * 160 + cl;
            float v = pd[(size_t)c * 288 + mthird * 96 + ml];
            Abuf[ml * 168 + cl] = f2bf(v);
        }
        __syncthreads();

        #pragma unroll
        for (int ksl = 0; ksl < 5; ++ksl) {
            // B fragment: 8 channel-values (k contiguous) for token col lr
            const float* bp0 = xn + (size_t)(p * 160 + ksl * 32 + lg * 8) * 4096 + hw0 + lr;
            s8v b0;
            #pragma unroll
            for (int e = 0; e < 8; ++e) {
                float v0 = bp0[(size_t)e * 4096];
                m0v = fmaxf(m0v, fabsf(v0));
                b0[e] = (short)f2bf(v0);
            }
            #pragma unroll
            for (int mt = 0; mt < 6; ++mt) {
                s8v a = *(s8v*)&Abuf[(mt * 16 + lr) * 168 + ksl * 32 + lg * 8];
                acc[mt] = __builtin_amdgcn_mfma_f32_16x16x32_bf16(a, b0, acc[mt], 0, 0, 0);
            }
        }
    }

    // per-token channel max: reduce across the 4 lg groups (lane bits 4,5)
    if (mthird == 0) {                      // other mthirds see the same x; store once
        m0v = fmaxf(m0v, __shfl_xor(m0v, 16, 64));
        m0v = fmaxf(m0v, __shfl_xor(m0v, 32, 64));
        if (lg == 0) mb[(n << 12) + hw0 + lr] = m0v;
    }

    // store S fp16: row = mthird*96 + mt*16 + lg*4 + r, col = n*4096 + hw0 + lr
    int colbase = (n << 12) + hw0 + lr;
    #pragma unroll
    for (int mt = 0; mt < 6; ++mt)
        #pragma unroll
        for (int r = 0; r < 4; ++r) {
            int row = mthird * 96 + mt * 16 + lg * 4 + r;
            Sh[(size_t)row * NTOK + colbase] = __float2half_rn(acc[mt][r]);
        }
}

// ---------------- int8 MFMA GEMM (round-8 proven): BK=128 swizzled LDS + XCD co-location ----------------
__global__ __launch_bounds__(256) void k_gemm(const int8_t* __restrict__ qx,
                                              const int8_t* __restrict__ qw,
                                              const float* __restrict__ sx,
                                              const float* __restrict__ sw,
                                              float* __restrict__ out) {
    __shared__ int8_t lsA[2][64 * BK];    // 2 x 8192 B
    __shared__ int8_t lsB[2][128 * BK];   // 2 x 16384 B
    int tid = threadIdx.x;
    int lid = blockIdx.x + 3 * blockIdx.y;  // 0..767
    int xcd = lid & 7, pos = lid >> 3;      // pos 0..95
    int n0 = (pos % 3) * 128;
    int m0 = (xcd * 32 + pos / 3) * 64;
    int wid = tid >> 6, lane = tid & 63;
    int wr = wid >> 1, wc = wid & 1;
    int lg = lane >> 4, lr = lane & 15;

    int srow = lane >> 3;                  // 0..7
    int sslot = (lane & 7) ^ srow;         // pre-swizzled global slot
    const int8_t* gA = qx + (size_t)m0 * KPAD;
    const int8_t* gB = qw + (size_t)n0 * KPAD;

    vi4 acc[2][4];
    #pragma unroll
    for (int i = 0; i < 2; ++i)
        #pragma unroll
        for (int j = 0; j < 4; ++j) acc[i][j] = (vi4)0;

    // prologue: stage tile 0 into buffer 0
    #pragma unroll
    for (int i = 0; i < 2; ++i) {   // A: 8 chunks, wave handles wid, wid+4
        int c = wid + i * 4;
        async16(gA + (size_t)(c * 8 + srow) * KPAD + sslot * 16, &lsA[0][c * 1024]);
    }
    #pragma unroll
    for (int i = 0; i < 4; ++i) {   // B: 16 chunks, wave handles wid+4i
        int c = wid + i * 4;
        async16(gB + (size_t)(c * 8 + srow) * KPAD + sslot * 16, &lsB[0][c * 1024]);
    }
    __syncthreads();

    int cur = 0;
    for (int kk = BK; kk < KPAD; kk += BK) {
        int nxt = cur ^ 1;
        #pragma unroll
        for (int i = 0; i < 2; ++i) {
            int c = wid + i * 4;
            async16(gA + (size_t)(c * 8 + srow) * KPAD + kk + sslot * 16, &lsA[nxt][c * 1024]);
        }
        #pragma unroll
        for (int i = 0; i < 4; ++i) {
            int c = wid + i * 4;
            async16(gB + (size_t)(c * 8 + srow) * KPAD + kk + sslot * 16, &lsB[nxt][c * 1024]);
        }
        // compute on current buffer while DMA is in flight
        #pragma unroll
        for (int k2 = 0; k2 < 2; ++k2) {
            vi4 af[2], bf[4];
            #pragma unroll
            for (int mi = 0; mi < 2; ++mi) {
                int row = wr * 32 + mi * 16 + lr;
                af[mi] = *(vi4*)&lsA[cur][row * BK + (((k2 * 4 + lg) ^ (lr & 7)) << 4)];
            }
            #pragma unroll
            for (int ni = 0; ni < 4; ++ni) {
                int row = wc * 64 + ni * 16 + lr;
                bf[ni] = *(vi4*)&lsB[cur][row * BK + (((k2 * 4 + lg) ^ (lr & 7)) << 4)];
            }
            #pragma unroll
            for (int mi = 0; mi < 2; ++mi)
                #pragma unroll
                for (int ni = 0; ni < 4; ++ni)
                    acc[mi][ni] = __builtin_amdgcn_mfma_i32_16x16x64_i8(af[mi], bf[ni], acc[mi][ni], 0, 0, 0);
        }
        __syncthreads();   // drains nxt staging; guards cur reuse next iter
        cur = nxt;
    }
    // last tile
    #pragma unroll
    for (int k2 = 0; k2 < 2; ++k2) {
        vi4 af[2], bf[4];
        #pragma unroll
        for (int mi = 0; mi < 2; ++mi) {
            int row = wr * 32 + mi * 16 + lr;
            af[mi] = *(vi4*)&lsA[cur][row * BK + (((k2 * 4 + lg) ^ (lr & 7)) << 4)];
        }
        #pragma unroll
        for (int ni = 0; ni < 4; ++ni) {
            int row = wc * 64 + ni * 16 + lr;
            bf[ni] = *(vi4*)&lsB[cur][row * BK + (((k2 * 4 + lg) ^ (lr & 7)) << 4)];
        }
        #pragma unroll
        for (int mi = 0; mi < 2; ++mi)
            #pragma unroll
            for (int ni = 0; ni < 4; ++ni)
                acc[mi][ni] = __builtin_amdgcn_mfma_i32_16x16x64_i8(af[mi], bf[ni], acc[mi][ni], 0, 0, 0);
    }

    float swv[4];
    #pragma unroll
    for (int ni = 0; ni < 4; ++ni) swv[ni] = sw[n0 + wc * 64 + ni * 16 + lr];
    #pragma unroll
    for (int mi = 0; mi < 2; ++mi) {
        int rbase = m0 + wr * 32 + mi * 16 + lg * 4;
        #pragma unroll
        for (int r = 0; r < 4; ++r) {
            int row = rbase + r;
            float sxv = sx[row];
            #pragma unroll
            for (int ni = 0; ni < 4; ++ni) {
                int col = n0 + wc * 64 + ni * 16 + lr;
                out[(size_t)row * OUT_F + col] = ((float)acc[mi][ni][r] * sxv) * swv[ni];
            }
        }
    }
}

// ---------------- epilogue v13: LDS-staged tap window ----------------
// Old rs-fill: 4.7M scattered 2B loads from Sh (9 taps x 1024 (tt,j) x 512
// blocks, stride-NTOK addressing, 2B used per cacheline touch). Per block the
// needed window is tiny and contiguous: per (u,j) S-row, 34 consecutive fp16
// (w0-1..w0+32 with the u-specific h shift) = 19.6 KB/block. v13 stages that
// window cooperatively (coalesced 68B runs, boundary slots pre-zeroed), then
// rs[tt][j] = sum_u sbuf[u][j][tt+u%3] -- same u-ascending order; padding
// contributes +0.0f exactly where the old code skipped the add (s is never
// -0) -> bit-identical output.
__global__ __launch_bounds__(384) void k_epi(float* __restrict__ out,
                                             const __half* __restrict__ Sh,
                                             const float* __restrict__ up,
                                             const float* __restrict__ bias) {
    __shared__ __half sbuf[9][32][36];    // 20736 B (c = 0..33, pad to 36)
    __shared__ float rs[32][RANK];        // 4 KB
    int tid = threadIdx.x;                // 0..383
    int o = tid;
    float uc[RANK];
    #pragma unroll
    for (int j = 0; j < RANK; ++j) uc[j] = up[(size_t)j * OUT_F + o];
    float b = bias[o];
    int t0 = blockIdx.x * 32;
    int n12 = t0 & ~4095;
    int hw = t0 & 4095, h = hw >> 6, w0 = hw & 63;   // 32 tokens of one image row

    // stage tap window: 9 u-rows x 32 ranks x 34 w-positions
    for (int i = tid; i < 9 * 32 * 34; i += 384) {
        int u = i / (32 * 34), rem = i - u * (32 * 34);
        int j = rem / 34, c = rem - j * 34;
        int hh = h + u / 3 - 1;
        int wv = w0 - 1 + c;
        __half v = __float2half_rn(0.f);
        if ((unsigned)hh < (unsigned)HH && (unsigned)wv < (unsigned)WW)
            v = Sh[(size_t)(u * 32 + j) * NTOK + n12 + (hh << 6) + wv];
        sbuf[u][j][c] = v;
    }
    __syncthreads();

    for (int i = tid; i < 32 * RANK; i += 384) {
        int tt = i & 31, j = i >> 5;
        float s = 0.f;
        #pragma unroll
        for (int u = 0; u < 9; ++u)      // u-ascending: same order as before
            s += __half2float(sbuf[u][j][tt + u % 3]);
        rs[tt][j] = s;
    }
    __syncthreads();
    for (int tt = 0; tt < 32; ++tt) {
        int t = t0 + tt;
        float a = out[(size_t)t * OUT_F + o];
        float l = 0.f;
        const v4f* rv = (const v4f*)&rs[tt][0];
        #pragma unroll
        for (int j4 = 0; j4 < 8; ++j4) {
            v4f r4 = rv[j4];
            l = fmaf(r4[0], uc[4 * j4 + 0], l);
            l = fmaf(r4[1], uc[4 * j4 + 1], l);
            l = fmaf(r4[2], uc[4 * j4 + 2], l);
            l = fmaf(r4[3], uc[4 * j4 + 3], l);
        }
        out[(size_t)t * OUT_F + o] = a + l + b;
    }
}

extern "C" void kernel_launch(void* const* d_in, const int* in_sizes, int n_in,
                              void* d_out, int out_size, void* d_ws, size_t ws_size,
                              hipStream_t stream) {
    const float* x    = (const float*)d_in[0];
    const float* w    = (const float*)d_in[1];
    const float* pd   = (const float*)d_in[2];
    const float* pu   = (const float*)d_in[3];
    const float* bias = (const float*)d_in[4];
    float* out = (float*)d_out;

    char* ws = (char*)d_ws;
    int8_t* qw    = (int8_t*)(ws + 0);           // 1,130,496
    float*  sw    = (float*) (ws + 1130496);     // 1,536
    float*  mb    = (float*) (ws + 1132032);     // 16384*4 = 65,536
    float*  sx    = (float*) (ws + 1656320);     // 65,536
    int8_t* qx    = (int8_t*)(ws + 1721856);     // 48,234,496
    __half* Sh    = (__half*)(ws + 49956352);    // 288*16384*2 = 9,437,184 (end 59,393,536)

    hipLaunchKernelGGL(kq_w,   dim3(OUT_F),    dim3(256), 0, stream, w, qw, sw);
    hipLaunchKernelGGL(k_down, dim3(3, 256),   dim3(256), 0, stream, x, pd, Sh, mb);
    hipLaunchKernelGGL(k_sx,   dim3(64),       dim3(256), 0, stream, mb, sx);
    hipLaunchKernelGGL(k_im2q, dim3(64, NCH),  dim3(256), 0, stream, x, sx, qx);
    hipLaunchKernelGGL(k_gemm, dim3(3, 256),   dim3(256), 0, stream, qx, qw, sx, sw, out);
    hipLaunchKernelGGL(k_epi,  dim3(512),      dim3(384), 0, stream, out, Sh, pu, bias);
}

// Round 17
// 179.891 us; speedup vs baseline: 1.0190x; 1.0190x over previous
//
#include <hip/hip_runtime.h>
#include <hip/hip_fp16.h>
#include <hip/hip_bf16.h>
#include <stdint.h>
#include <stddef.h>

#define C_INC 320
#define KREAL 2880
#define KPAD  2944
#define OUT_F 384
#define RANK  32
#define HH    64
#define WW    64
#define NTOK  16384
#define NCH   16         // channel chunks for im2q kernel
#define CCH   20         // channels per chunk (16*20=320)
#define QSTR  76         // qbuf row stride bytes (max 8ch*9=72 +4 pad)
#define BK    128        // k_gemm K-tile

typedef int   vi4 __attribute__((ext_vector_type(4)));
typedef float v4f __attribute__((ext_vector_type(4)));
typedef short s8v __attribute__((ext_vector_type(8)));

// async global->LDS, 16B per lane; LDS dest is wave-uniform base + lane*16
static __device__ __forceinline__ void async16(const void* g, void* l) {
    __builtin_amdgcn_global_load_lds(
        (const __attribute__((address_space(1))) unsigned int*)g,
        (__attribute__((address_space(3))) unsigned int*)l, 16, 0, 0);
}

static __device__ __forceinline__ unsigned short f2bf(float f) {
    __hip_bfloat16 h = __float2bfloat16(f);   // RNE
    union { __hip_bfloat16 h; unsigned short u; } c; c.h = h; return c.u;
}

// ---------------- quantize weights per output row (exact IEEE div) ----------------
__global__ __launch_bounds__(256) void kq_w(const float* __restrict__ w,
                                            int8_t* __restrict__ qw,
                                            float* __restrict__ sw) {
    int o = blockIdx.x;
    const float* row = w + (size_t)o * KPAD;
    float m = 0.f;
    for (int k = threadIdx.x; k < KPAD; k += 256) m = fmaxf(m, fabsf(row[k]));
    #pragma unroll
    for (int off = 32; off > 0; off >>= 1) m = fmaxf(m, __shfl_down(m, off, 64));
    __shared__ float red[4];
    __shared__ float sval;
    if ((threadIdx.x & 63) == 0) red[threadIdx.x >> 6] = m;
    __syncthreads();
    if (threadIdx.x == 0) {
        float mm = fmaxf(fmaxf(red[0], red[1]), fmaxf(red[2], red[3]));
        sval = fmaxf(mm / 7.0f, 1e-8f);
        sw[o] = sval;
    }
    __syncthreads();
    float s = sval;
    for (int k = threadIdx.x; k < KPAD; k += 256) {
        float q = rintf(row[k] / s);          // IEEE div + RNE, matches np
        q = fminf(fmaxf(q, -8.f), 7.f);
        qw[(size_t)o * KPAD + k] = (int8_t)q;
    }
}

// ---------------- sx = max over 3x3 neighborhood of per-pixel channel max / 7 ----------------
__global__ __launch_bounds__(256) void k_sx(const float* __restrict__ mb,
                                            float* __restrict__ sx) {
    int p = blockIdx.x * 256 + threadIdx.x;
    int n = p >> 12, hw = p & 4095;
    int h = hw >> 6, w = hw & 63;
    const float* pl = mb + (n << 12);
    float m = 0.f;
    #pragma unroll
    for (int di = -1; di <= 1; ++di)
        #pragma unroll
        for (int dj = -1; dj <= 1; ++dj) {
            int hh = h + di, ww = w + dj;
            if ((unsigned)hh < (unsigned)HH && (unsigned)ww < (unsigned)WW)
                m = fmaxf(m, pl[(hh << 6) + ww]);
        }
    sx[p] = fmaxf(m / 7.0f, 1e-8f);
}

// ---------------- im2col quantize only ----------------
__global__ __launch_bounds__(256) void k_im2q(const float* __restrict__ x,
                                              const float* __restrict__ sx,
                                              int8_t* __restrict__ qx) {
    __shared__ int8_t qbuf[256 * QSTR];    // 19456 B (256 token rows)
    const int pstart[4] = {0, 8, 16, 20};  // phase channel starts (sizes 8,8,4)
    const int phoff[3]  = {0, 72, 144};    // byte offset within this chunk's k-range

    int tid = threadIdx.x;                 // 0..255
    int rg = blockIdx.x;                   // 0..63
    int cc = blockIdx.y;                   // 0..15
    int n = rg >> 4, h4 = rg & 15;
    int wid = tid >> 6, lane = tid & 63;
    int ha = h4 * 4 + wid;                 // this thread's image row
    int c0 = cc * CCH;

    int ta = (n << 12) + (ha << 6) + lane; // this thread's token
    float inva = 1.0f / sx[ta];
    const float* xrowa = x + ((size_t)(n * C_INC) + c0) * 4096 + (ha << 6) + lane;
    bool hok0a = (ha > 0), hok2a = (ha < 63);
    bool wok0 = (lane > 0), wok2 = (lane < 63);
    int bt = (n << 12) + (h4 << 8);        // block's first token (4 rows * 64)
    int qra = tid;                          // qbuf row for this token

    for (int ph = 0; ph < 3; ++ph) {
        int ps = pstart[ph], pch = pstart[ph + 1] - ps;
        __syncthreads();   // prior phase's qbuf writes complete
        if (ph > 0) {      // flush previous phase (8 ch = 18 dwords/row, 256 rows)
            for (int i = tid; i < 256 * 18; i += 256) {
                int row = i / 18, col = i - row * 18;
                *(unsigned int*)&qx[(size_t)(bt + row) * KPAD + cc * 180 + phoff[ph - 1] + col * 4] =
                    *(unsigned int*)&qbuf[row * QSTR + col * 4];
            }
        }
        __syncthreads();   // flush reads done before qbuf overwrite

        // initial row loads for this phase
        const float* xca = xrowa + (size_t)ps * 4096;
        float r0a = hok0a ? xca[-64] : 0.f, r1a = xca[0], r2a = hok2a ? xca[64] : 0.f;

        for (int cl = 0; cl < pch; ++cl) {
            // prefetch next channel's rows
            float p0a = 0.f, p1a = 0.f, p2a = 0.f;
            if (cl + 1 < pch) {
                const float* xna = xrowa + (size_t)(ps + cl + 1) * 4096;
                p0a = hok0a ? xna[-64] : 0.f; p1a = xna[0]; p2a = hok2a ? xna[64] : 0.f;
            }
            // horizontal neighbors: shfl executed by ALL lanes, then select
            float va[9];
            {
                float u0 = __shfl_up(r0a, 1, 64), d0 = __shfl_down(r0a, 1, 64);
                float u1 = __shfl_up(r1a, 1, 64), d1 = __shfl_down(r1a, 1, 64);
                float u2 = __shfl_up(r2a, 1, 64), d2 = __shfl_down(r2a, 1, 64);
                va[0] = wok0 ? u0 : 0.f; va[1] = r0a; va[2] = wok2 ? d0 : 0.f;
                va[3] = wok0 ? u1 : 0.f; va[4] = r1a; va[5] = wok2 ? d1 : 0.f;
                va[6] = wok0 ? u2 : 0.f; va[7] = r2a; va[8] = wok2 ? d2 : 0.f;
            }
            #pragma unroll
            for (int u = 0; u < 9; ++u) {
                float qa = rintf(va[u] * inva);
                qa = fminf(fmaxf(qa, -8.f), 7.f);
                qbuf[qra * QSTR + cl * 9 + u] = (int8_t)qa;
            }
            r0a = p0a; r1a = p1a; r2a = p2a;
        }
    }

    // flush phase 2 (4 ch = 9 dwords; cc==15 adds 16 zero dwords for k-pad)
    __syncthreads();
    if (cc == NCH - 1) {
        for (int i = tid; i < 256 * 25; i += 256) {
            int row = i / 25, col = i - row * 25;
            unsigned int vdw = (col < 9) ? *(unsigned int*)&qbuf[row * QSTR + col * 4] : 0u;
            *(unsigned int*)&qx[(size_t)(bt + row) * KPAD + cc * 180 + 144 + col * 4] = vdw;
        }
    } else {
        for (int i = tid; i < 256 * 9; i += 256) {
            int row = i / 9, col = i - row * 9;
            *(unsigned int*)&qx[(size_t)(bt + row) * KPAD + cc * 180 + 144 + col * 4] =
                *(unsigned int*)&qbuf[row * QSTR + col * 4];
        }
    }
}

// ---------------- k_down v13: 3x96 m-split + software-pipelined gather ----------------
// v12 (round 15, measured win) left the in-wave dependent chain: per ksl,
// 8 strided L2 loads (~200cy) -> cvt -> 6 MFMAs (~48cy), loads on the
// critical path. v13 prefetches the NEXT ksl group's 8 values before
// computing the current one (k_im2q's proven pattern), hiding the L2
// latency under cvt+MFMA. Prefetch stays within each p-phase (4/5 steps
// covered; p-boundary keeps its Abuf barrier). Values, fmax order and MFMA
// sequence unchanged -> bit-identical Sh/mb.
__global__ __launch_bounds__(256) void k_down(const float* __restrict__ x,
                                              const float* __restrict__ pd,
                                              __half* __restrict__ Sh,
                                              float* __restrict__ mb) {
    __shared__ unsigned short Abuf[96 * 168];    // 32256 B, row=ml, col=phase-local c (pad 160->168)
    int tid = threadIdx.x;
    int lid = blockIdx.x + 3 * blockIdx.y;  // 0..767
    int xcd = lid & 7, pos = lid >> 3;      // pos 0..95
    int mthird = pos % 3;                   // fastest: siblings adjacent on same XCD
    int nb = xcd * 32 + pos / 3;            // 0..255 (64-token chunk id)
    int w = tid >> 6, lane = tid & 63;
    int lg = lane >> 4, lr = lane & 15;
    int n = nb >> 6;                        // image index (64 chunks per image)
    int hw0 = (nb & 63) * 64 + w * 16;      // wave's 16-token span
    const float* xn = x + (size_t)n * (C_INC * 4096);

    v4f acc[6];
    #pragma unroll
    for (int mt = 0; mt < 6; ++mt) acc[mt] = (v4f)0.f;
    float m0v = 0.f;                        // channel absmax for this wave's 16 tokens

    for (int p = 0; p < 2; ++p) {
        __syncthreads();   // prior phase's a-frag reads complete
        // stage A: src pd slice is contiguous per channel: pd[c*288 + m_global]
        for (int i = tid; i < 160 * 96; i += 256) {
            int cl = i / 96, ml = i - cl * 96;
            int c = p * 160 + cl;
            float v = pd[(size_t)c * 288 + mthird * 96 + ml];
            Abuf[ml * 168 + cl] = f2bf(v);
        }
        __syncthreads();

        // initial gather for ksl=0
        float cv[8];
        {
            const float* bp0 = xn + (size_t)(p * 160 + lg * 8) * 4096 + hw0 + lr;
            #pragma unroll
            for (int e = 0; e < 8; ++e) cv[e] = bp0[(size_t)e * 4096];
        }
        #pragma unroll
        for (int ksl = 0; ksl < 5; ++ksl) {
            // prefetch next ksl group (hides L2 latency under cvt+MFMA)
            float pv[8];
            if (ksl < 4) {
                const float* bpn = xn + (size_t)(p * 160 + (ksl + 1) * 32 + lg * 8) * 4096 + hw0 + lr;
                #pragma unroll
                for (int e = 0; e < 8; ++e) pv[e] = bpn[(size_t)e * 4096];
            }
            s8v b0;
            #pragma unroll
            for (int e = 0; e < 8; ++e) {
                m0v = fmaxf(m0v, fabsf(cv[e]));
                b0[e] = (short)f2bf(cv[e]);
            }
            #pragma unroll
            for (int mt = 0; mt < 6; ++mt) {
                s8v a = *(s8v*)&Abuf[(mt * 16 + lr) * 168 + ksl * 32 + lg * 8];
                acc[mt] = __builtin_amdgcn_mfma_f32_16x16x32_bf16(a, b0, acc[mt], 0, 0, 0);
            }
            if (ksl < 4) {
                #pragma unroll
                for (int e = 0; e < 8; ++e) cv[e] = pv[e];
            }
        }
    }

    // per-token channel max: reduce across the 4 lg groups (lane bits 4,5)
    if (mthird == 0) {                      // other mthirds see the same x; store once
        m0v = fmaxf(m0v, __shfl_xor(m0v, 16, 64));
        m0v = fmaxf(m0v, __shfl_xor(m0v, 32, 64));
        if (lg == 0) mb[(n << 12) + hw0 + lr] = m0v;
    }

    // store S fp16: row = mthird*96 + mt*16 + lg*4 + r, col = n*4096 + hw0 + lr
    int colbase = (n << 12) + hw0 + lr;
    #pragma unroll
    for (int mt = 0; mt < 6; ++mt)
        #pragma unroll
        for (int r = 0; r < 4; ++r) {
            int row = mthird * 96 + mt * 16 + lg * 4 + r;
            Sh[(size_t)row * NTOK + colbase] = __float2half_rn(acc[mt][r]);
        }
}

// ---------------- int8 MFMA GEMM (round-8 proven): BK=128 swizzled LDS + XCD co-location ----------------
__global__ __launch_bounds__(256) void k_gemm(const int8_t* __restrict__ qx,
                                              const int8_t* __restrict__ qw,
                                              const float* __restrict__ sx,
                                              const float* __restrict__ sw,
                                              float* __restrict__ out) {
    __shared__ int8_t lsA[2][64 * BK];    // 2 x 8192 B
    __shared__ int8_t lsB[2][128 * BK];   // 2 x 16384 B
    int tid = threadIdx.x;
    int lid = blockIdx.x + 3 * blockIdx.y;  // 0..767
    int xcd = lid & 7, pos = lid >> 3;      // pos 0..95
    int n0 = (pos % 3) * 128;
    int m0 = (xcd * 32 + pos / 3) * 64;
    int wid = tid >> 6, lane = tid & 63;
    int wr = wid >> 1, wc = wid & 1;
    int lg = lane >> 4, lr = lane & 15;

    int srow = lane >> 3;                  // 0..7
    int sslot = (lane & 7) ^ srow;         // pre-swizzled global slot
    const int8_t* gA = qx + (size_t)m0 * KPAD;
    const int8_t* gB = qw + (size_t)n0 * KPAD;

    vi4 acc[2][4];
    #pragma unroll
    for (int i = 0; i < 2; ++i)
        #pragma unroll
        for (int j = 0; j < 4; ++j) acc[i][j] = (vi4)0;

    // prologue: stage tile 0 into buffer 0
    #pragma unroll
    for (int i = 0; i < 2; ++i) {   // A: 8 chunks, wave handles wid, wid+4
        int c = wid + i * 4;
        async16(gA + (size_t)(c * 8 + srow) * KPAD + sslot * 16, &lsA[0][c * 1024]);
    }
    #pragma unroll
    for (int i = 0; i < 4; ++i) {   // B: 16 chunks, wave handles wid+4i
        int c = wid + i * 4;
        async16(gB + (size_t)(c * 8 + srow) * KPAD + sslot * 16, &lsB[0][c * 1024]);
    }
    __syncthreads();

    int cur = 0;
    for (int kk = BK; kk < KPAD; kk += BK) {
        int nxt = cur ^ 1;
        #pragma unroll
        for (int i = 0; i < 2; ++i) {
            int c = wid + i * 4;
            async16(gA + (size_t)(c * 8 + srow) * KPAD + kk + sslot * 16, &lsA[nxt][c * 1024]);
        }
        #pragma unroll
        for (int i = 0; i < 4; ++i) {
            int c = wid + i * 4;
            async16(gB + (size_t)(c * 8 + srow) * KPAD + kk + sslot * 16, &lsB[nxt][c * 1024]);
        }
        // compute on current buffer while DMA is in flight
        #pragma unroll
        for (int k2 = 0; k2 < 2; ++k2) {
            vi4 af[2], bf[4];
            #pragma unroll
            for (int mi = 0; mi < 2; ++mi) {
                int row = wr * 32 + mi * 16 + lr;
                af[mi] = *(vi4*)&lsA[cur][row * BK + (((k2 * 4 + lg) ^ (lr & 7)) << 4)];
            }
            #pragma unroll
            for (int ni = 0; ni < 4; ++ni) {
                int row = wc * 64 + ni * 16 + lr;
                bf[ni] = *(vi4*)&lsB[cur][row * BK + (((k2 * 4 + lg) ^ (lr & 7)) << 4)];
            }
            #pragma unroll
            for (int mi = 0; mi < 2; ++mi)
                #pragma unroll
                for (int ni = 0; ni < 4; ++ni)
                    acc[mi][ni] = __builtin_amdgcn_mfma_i32_16x16x64_i8(af[mi], bf[ni], acc[mi][ni], 0, 0, 0);
        }
        __syncthreads();   // drains nxt staging; guards cur reuse next iter
        cur = nxt;
    }
    // last tile
    #pragma unroll
    for (int k2 = 0; k2 < 2; ++k2) {
        vi4 af[2], bf[4];
        #pragma unroll
        for (int mi = 0; mi < 2; ++mi) {
            int row = wr * 32 + mi * 16 + lr;
            af[mi] = *(vi4*)&lsA[cur][row * BK + (((k2 * 4 + lg) ^ (lr & 7)) << 4)];
        }
        #pragma unroll
        for (int ni = 0; ni < 4; ++ni) {
            int row = wc * 64 + ni * 16 + lr;
            bf[ni] = *(vi4*)&lsB[cur][row * BK + (((k2 * 4 + lg) ^ (lr & 7)) << 4)];
        }
        #pragma unroll
        for (int mi = 0; mi < 2; ++mi)
            #pragma unroll
            for (int ni = 0; ni < 4; ++ni)
                acc[mi][ni] = __builtin_amdgcn_mfma_i32_16x16x64_i8(af[mi], bf[ni], acc[mi][ni], 0, 0, 0);
    }

    float swv[4];
    #pragma unroll
    for (int ni = 0; ni < 4; ++ni) swv[ni] = sw[n0 + wc * 64 + ni * 16 + lr];
    #pragma unroll
    for (int mi = 0; mi < 2; ++mi) {
        int rbase = m0 + wr * 32 + mi * 16 + lg * 4;
        #pragma unroll
        for (int r = 0; r < 4; ++r) {
            int row = rbase + r;
            float sxv = sx[row];
            #pragma unroll
            for (int ni = 0; ni < 4; ++ni) {
                int col = n0 + wc * 64 + ni * 16 + lr;
                out[(size_t)row * OUT_F + col] = ((float)acc[mi][ni][r] * sxv) * swv[ni];
            }
        }
    }
}

// ---------------- epilogue: out += gather9(S) @ up + bias (round-15 proven) ----------------
// Round-16 LDS-staging experiment REGRESSED (181->183): Sh gathers were
// already L2/L3-absorbed at 2 blocks/CU TLP; staging barriers cost more
// than they saved. Reverted.
__global__ __launch_bounds__(384) void k_epi(float* __restrict__ out,
                                             const __half* __restrict__ Sh,
                                             const float* __restrict__ up,
                                             const float* __restrict__ bias) {
    __shared__ float rs[32][RANK];        // 4 KB
    int tid = threadIdx.x;                // 0..383
    int o = tid;
    float uc[RANK];
    #pragma unroll
    for (int j = 0; j < RANK; ++j) uc[j] = up[(size_t)j * OUT_F + o];
    float b = bias[o];
    int t0 = blockIdx.x * 32;
    for (int i = tid; i < 32 * RANK; i += 384) {
        int tt = i & 31, j = i >> 5;
        int t = t0 + tt;
        int n12 = t & ~4095;
        int hw = t & 4095, h = hw >> 6, w = hw & 63;
        float s = 0.f;
        #pragma unroll
        for (int u = 0; u < 9; ++u) {
            int hh = h + u / 3 - 1, wv = w + u % 3 - 1;
            if ((unsigned)hh < (unsigned)HH && (unsigned)wv < (unsigned)WW)
                s += __half2float(Sh[(size_t)(u * 32 + j) * NTOK + n12 + (hh << 6) + wv]);
        }
        rs[tt][j] = s;
    }
    __syncthreads();
    for (int tt = 0; tt < 32; ++tt) {
        int t = t0 + tt;
        float a = out[(size_t)t * OUT_F + o];
        float l = 0.f;
        const v4f* rv = (const v4f*)&rs[tt][0];
        #pragma unroll
        for (int j4 = 0; j4 < 8; ++j4) {
            v4f r4 = rv[j4];
            l = fmaf(r4[0], uc[4 * j4 + 0], l);
            l = fmaf(r4[1], uc[4 * j4 + 1], l);
            l = fmaf(r4[2], uc[4 * j4 + 2], l);
            l = fmaf(r4[3], uc[4 * j4 + 3], l);
        }
        out[(size_t)t * OUT_F + o] = a + l + b;
    }
}

extern "C" void kernel_launch(void* const* d_in, const int* in_sizes, int n_in,
                              void* d_out, int out_size, void* d_ws, size_t ws_size,
                              hipStream_t stream) {
    const float* x    = (const float*)d_in[0];
    const float* w    = (const float*)d_in[1];
    const float* pd   = (const float*)d_in[2];
    const float* pu   = (const float*)d_in[3];
    const float* bias = (const float*)d_in[4];
    float* out = (float*)d_out;

    char* ws = (char*)d_ws;
    int8_t* qw    = (int8_t*)(ws + 0);           // 1,130,496
    float*  sw    = (float*) (ws + 1130496);     // 1,536
    float*  mb    = (float*) (ws + 1132032);     // 16384*4 = 65,536
    float*  sx    = (float*) (ws + 1656320);     // 65,536
    int8_t* qx    = (int8_t*)(ws + 1721856);     // 48,234,496
    __half* Sh    = (__half*)(ws + 49956352);    // 288*16384*2 = 9,437,184 (end 59,393,536)

    hipLaunchKernelGGL(kq_w,   dim3(OUT_F),    dim3(256), 0, stream, w, qw, sw);
    hipLaunchKernelGGL(k_down, dim3(3, 256),   dim3(256), 0, stream, x, pd, Sh, mb);
    hipLaunchKernelGGL(k_sx,   dim3(64),       dim3(256), 0, stream, mb, sx);
    hipLaunchKernelGGL(k_im2q, dim3(64, NCH),  dim3(256), 0, stream, x, sx, qx);
    hipLaunchKernelGGL(k_gemm, dim3(3, 256),   dim3(256), 0, stream, qx, qw, sx, sw, out);
    hipLaunchKernelGGL(k_epi,  dim3(512),      dim3(384), 0, stream, out, Sh, pu, bias);
}